// Round 10
// baseline (122.177 us; speedup 1.0000x reference)
//
#include <hip/hip_runtime.h>
#include <hip/hip_fp16.h>

// MinibatchDiscrimination  B=256, IN_F=1024, OUT_F=128, KD=16 (fp32 in/out)
// out[b] = concat(x[b], o_b[b]); o_b[b][o] = sum_b2 exp(-L1(m[b,o,:], m[b2,o,:])) - 1
//
// R10: DESIGNED MEASUREMENT ROUND. R8->R9 micro-opts (register prefetch in
// k_gemm, 4-row amortization in k_pair) were both no-ops (-0.6 us vs -12
// predicted); exec total ~30 us vs ~9 us bottom-up model, and both kernels sit
// below the 40-us fills so rocprof top-5 can't see the g/p split. Kernels are
// idempotent (pure, no atomics) -> launch k_gemm x3 + k_pair x1, kernels
// byte-identical to R9. g = (dur10 - dur9 - dGap)/2, dGap in [0, 4.4].
// Hypothesis->dur: (g20,p10)->132, (g15,p15)->122, (g8,p22)->108, (g5,p25)->100.
// Numerics (R1-R9, absmax=0.0): cross-pair norms ~580 -> expf underflows to
// exact 0; self-pair diff bitwise 0 (same LDS row) -> +1 exactly, -1 at end.

#define BATCH 256
#define INF   1024
#define OUTF  128
#define KDIM  16
#define TCOLS 2048
#define OCOLS 1152
#define XB    1032   // bs row = 2064 B = 129*16: 16B-aligned, bank shift 4/row,
                     // b128 frag reads <=2-way aliased = free (m136)

typedef __attribute__((ext_vector_type(8))) short short8;
typedef __attribute__((ext_vector_type(4))) float f32x4;

// pack two fp32 -> two bf16 (trunc) in one v_perm: low16 = lo, high16 = hi
__device__ inline unsigned pack_bf2(float lo, float hi) {
    return __builtin_amdgcn_perm(__float_as_uint(hi), __float_as_uint(lo), 0x07060302u);
}
__device__ inline unsigned short bf_trunc(float f) {
    return (unsigned short)(__float_as_uint(f) >> 16);
}

// ---------------------------------------------------------------- k_gemm
// Block = (o 0..127, mq 0..3), 256 thr = 4 waves; wave w -> m-tile mq*4+w.
// B-slice staged once to LDS bf16; K-loop: A-frags from global x via 4-stage
// register prefetch (8 float4 outstanding), in-register fp32->bf16 cvt.
// 512 blocks = 2 blk/CU = 8 waves/CU.  [byte-identical to R9]
__global__ __launch_bounds__(256, 2) void k_gemm(const float* __restrict__ x,
                                                 const float* __restrict__ T,
                                                 __half* __restrict__ mh) {
    const int blk = blockIdx.x;
    const int o   = blk & 127;
    const int mq  = blk >> 7;
    const int tid = threadIdx.x;
    const int wave = tid >> 6, lane = tid & 63;
    const int l15 = lane & 15, q = lane >> 4;

    __shared__ unsigned short bs[16][XB];   // 33,024 B
    __shared__ __half pmout[64][16];        //  2,048 B

    // stage B: bs[n][k] = bf16(T[k][o*16+n]); 16 passes x 64 k-rows
    {
        const int kb = tid >> 2, n0 = (tid & 3) * 4;
        #pragma unroll
        for (int pass = 0; pass < 16; ++pass) {
            const int k = pass * 64 + kb;
            float4 v = *reinterpret_cast<const float4*>(&T[k * TCOLS + o * KDIM + n0]);
            bs[n0 + 0][k] = bf_trunc(v.x);
            bs[n0 + 1][k] = bf_trunc(v.y);
            bs[n0 + 2][k] = bf_trunc(v.z);
            bs[n0 + 3][k] = bf_trunc(v.w);
        }
    }
    __syncthreads();

    // K-loop with 4-stage register prefetch. A-frag: A[m=l15][k=q*8+j] (m89/m91).
    const int mt = mq * 4 + wave;
    const float* xr = &x[(mt * 16 + l15) * INF + q * 8];

    float4 st[4][2];
    #pragma unroll
    for (int p = 0; p < 4; ++p) {
        st[p][0] = *reinterpret_cast<const float4*>(xr + p * 32);
        st[p][1] = *reinterpret_cast<const float4*>(xr + p * 32 + 4);
    }
    f32x4 acc = {0.f, 0.f, 0.f, 0.f};
    #pragma unroll
    for (int ks = 0; ks < 32; ++ks) {
        const int p = ks & 3;
        float4 a0 = st[p][0], a1 = st[p][1];
        const int kn = (ks + 4 < 32) ? ks + 4 : ks;   // tail: dead reload, harmless
        st[p][0] = *reinterpret_cast<const float4*>(xr + kn * 32);
        st[p][1] = *reinterpret_cast<const float4*>(xr + kn * 32 + 4);
        short8 bfr = *reinterpret_cast<const short8*>(&bs[l15][ks * 32 + q * 8]);
        union { unsigned u[4]; short8 s; } ua;
        ua.u[0] = pack_bf2(a0.x, a0.y); ua.u[1] = pack_bf2(a0.z, a0.w);
        ua.u[2] = pack_bf2(a1.x, a1.y); ua.u[3] = pack_bf2(a1.z, a1.w);
        acc = __builtin_amdgcn_mfma_f32_16x16x32_bf16(ua.s, bfr, acc, 0, 0, 0);
    }

    // D layout (m89/m91): col(=kd)=l15, row(=b in tile)=q*4+r
    #pragma unroll
    for (int r = 0; r < 4; ++r)
        pmout[wave * 16 + q * 4 + r][l15] = __float2half(acc[r]);
    __syncthreads();

    // coalesced copy-out -> mh[o][mq*64 + row][*]  (pairwise-native layout)
    if (tid < 128) {
        const int row = tid >> 1, hh = tid & 1;
        uint4 v = *reinterpret_cast<const uint4*>(&pmout[row][hh * 8]);
        *reinterpret_cast<uint4*>(&mh[o * (BATCH * KDIM) + (mq * 64 + row) * KDIM + hh * 8]) = v;
    }
}

// ---------------------------------------------------------------- k_pair
// Block = (o, h), 1024 thr. Thread: i1 = tid&31, bsel = tid>>5 (0..31);
// owns 4 b1-rows {h*128 + r*32 + i1} vs b2 in [bsel*8, bsel*8+8).
// [byte-identical to R9]
__global__ __launch_bounds__(1024) void k_pair(const float* __restrict__ x,
                                               const __half* __restrict__ mh,
                                               float* __restrict__ out) {
    const int blk = blockIdx.x;
    const int o   = blk & 127;
    const int h   = blk >> 7;
    const int tid = threadIdx.x;

    __shared__ __half2 pm[BATCH][8];      //  8 KB
    __shared__ float part[32][128];       // 16 KB  [bsel][b1-local]

    // prologue: copy x row blk into out (cols 0..1023)
    if (tid < 256)
        reinterpret_cast<float4*>(out)[blk * 288 + tid] =
            reinterpret_cast<const float4*>(x)[blk * 256 + tid];

    // load m-slice: contiguous 8 KB, 512 x uint4
    if (tid < 512) {
        uint4 v = *reinterpret_cast<const uint4*>(
            &mh[o * (BATCH * KDIM) + (tid >> 1) * KDIM + (tid & 1) * 8]);
        *reinterpret_cast<uint4*>(&pm[tid >> 1][(tid & 1) * 4]) = v;
    }
    __syncthreads();

    const int i1 = tid & 31;
    const int bsel = tid >> 5;            // 0..31
    __half2 my[4][8];
    #pragma unroll
    for (int r = 0; r < 4; ++r) {
        union { uint4 u[2]; __half2 hh[8]; } c;
        c.u[0] = *reinterpret_cast<const uint4*>(&pm[h * 128 + r * 32 + i1][0]);
        c.u[1] = *reinterpret_cast<const uint4*>(&pm[h * 128 + r * 32 + i1][4]);
        #pragma unroll
        for (int j = 0; j < 8; ++j) my[r][j] = c.hh[j];
    }

    float tot[4] = {0.f, 0.f, 0.f, 0.f};
    const int b2_lo = bsel * 8;
    #pragma unroll
    for (int b2 = b2_lo; b2 < b2_lo + 8; ++b2) {
        union { uint4 u[2]; __half2 hh[8]; } co;      // wave-uniform -> broadcast
        co.u[0] = *reinterpret_cast<const uint4*>(&pm[b2][0]);
        co.u[1] = *reinterpret_cast<const uint4*>(&pm[b2][4]);
        #pragma unroll
        for (int r = 0; r < 4; ++r) {
            __half2 e0 = __habs2(__hsub2(my[r][0], co.hh[0]));
            __half2 e1 = __habs2(__hsub2(my[r][1], co.hh[1]));
            __half2 e2 = __habs2(__hsub2(my[r][2], co.hh[2]));
            __half2 e3 = __habs2(__hsub2(my[r][3], co.hh[3]));
            e0 = __hadd2(e0, __habs2(__hsub2(my[r][4], co.hh[4])));
            e1 = __hadd2(e1, __habs2(__hsub2(my[r][5], co.hh[5])));
            e2 = __hadd2(e2, __habs2(__hsub2(my[r][6], co.hh[6])));
            e3 = __hadd2(e3, __habs2(__hsub2(my[r][7], co.hh[7])));
            __half2 es = __hadd2(__hadd2(e0, e1), __hadd2(e2, e3));
            float n = __low2float(es) + __high2float(es);
            tot[r] += __expf(-n);   // b2==b1: same pm row -> diff bitwise 0 -> +1 exact
        }
    }
    #pragma unroll
    for (int r = 0; r < 4; ++r)
        part[bsel][r * 32 + i1] = tot[r];
    __syncthreads();

    // epilogue: sum 32 bsel partials; -1 removes self-pair. One writer per (b,o).
    if (tid < 128) {
        float s = -1.0f;
        #pragma unroll
        for (int j = 0; j < 32; ++j) s += part[j][tid];
        out[(h * 128 + tid) * OCOLS + INF + o] = s;
    }
}

// ---------------------------------------------------------------- launch
// MEASUREMENT: k_gemm x3 (idempotent) + k_pair. dur arithmetic vs R9 yields
// the per-kernel split that the top-5 window cannot show.
extern "C" void kernel_launch(void* const* d_in, const int* in_sizes, int n_in,
                              void* d_out, int out_size, void* d_ws, size_t ws_size,
                              hipStream_t stream) {
    const float* x = (const float*)d_in[0];   // [256][1024]
    const float* T = (const float*)d_in[1];   // [1024][2048]
    float* out = (float*)d_out;               // [256][1152]
    __half* mh = (__half*)d_ws;               // [128][256][16] fp16 = 1 MB

    k_gemm<<<512, 256, 0, stream>>>(x, T, mh);
    k_gemm<<<512, 256, 0, stream>>>(x, T, mh);
    k_gemm<<<512, 256, 0, stream>>>(x, T, mh);
    k_pair<<<256, 1024, 0, stream>>>(x, mh, out);
}

// Round 12
// 88.210 us; speedup vs baseline: 1.3851x; 1.3851x over previous
//
#include <hip/hip_runtime.h>
#include <hip/hip_fp16.h>

// MinibatchDiscrimination  B=256, IN_F=1024, OUT_F=128, KD=16 (fp32 in/out)
// out[b] = concat(x[b], o_b[b]); o_b[b][o] = sum_b2 exp(-L1(m[b,o,:], m[b2,o,:])) - 1
//
// R12 = R11 with two ROCm-7.2 compile fixes (theory unchanged):
//   * __hmin2 missing in amd_hip_fp16.h -> inline-asm v_pk_min_f16 wrapper
//   * __exp2f collides with glibc macro -> __builtin_amdgcn_exp2f
// R11 theory (from R10's split measurement g=15, p=15):
//  - k_pair is VALU-ISSUE-bound: min-trick |a-b| = a+b-2min(a,b) ->
//    norm = S1+S2-2*sum(min), per-row S precomputed (log2e folded) ->
//    ~22 instr/triple vs ~30. Pred pair ~11 us.
//  - k_gemm L2-traffic bound: k_prep pre-converts x->xb bf16, T->tt bf16[n][k]
//    (+1 node +2.2 us); gemm loses B-stage/LDS/barrier, operand bytes halve,
//    4 waves/block share tt rows (L1 broadcast). Pred gemm ~7-9, prep ~2.5 us.
// Numerics: cross-pair norms ~580 -> exp2 arg ~ -840 -> underflows to exact 0
// (R1-R10 absmax 0.0). Self-pair residual ~1e-5 (S rounding vs min-chain);
// expected absmax ~1e-5..1e-4 << 0.099 threshold.

#define BATCH 256
#define INF   1024
#define OUTF  128
#define KDIM  16
#define TCOLS 2048
#define OCOLS 1152

typedef __attribute__((ext_vector_type(8))) short short8;
typedef __attribute__((ext_vector_type(4))) float f32x4;

__device__ inline unsigned short bf_trunc(float f) {
    return (unsigned short)(__float_as_uint(f) >> 16);
}
// pack two fp32 -> two bf16 (trunc) in one v_perm: low16 = lo, high16 = hi
__device__ inline unsigned pack_bf2(float lo, float hi) {
    return __builtin_amdgcn_perm(__float_as_uint(hi), __float_as_uint(lo), 0x07060302u);
}
// packed f16 min: instruction exists on gfx950, HIP wrapper doesn't (ROCm 7.2)
__device__ inline __half2 hmin2(__half2 a, __half2 b) {
    unsigned ua = *reinterpret_cast<unsigned*>(&a);
    unsigned ub = *reinterpret_cast<unsigned*>(&b);
    unsigned ud;
    asm("v_pk_min_f16 %0, %1, %2" : "=v"(ud) : "v"(ua), "v"(ub));
    return *reinterpret_cast<__half2*>(&ud);
}

// ---------------------------------------------------------------- k_prep
// blocks [0,512): transpose+cvt T[1024][2048] -> tt[2048][1024] bf16 (trunc)
// blocks [512,576): cvt x -> xb bf16.  (R3-proven code.)
#define TPAD 66
__global__ __launch_bounds__(256) void k_prep(const float* __restrict__ x,
                                              const float* __restrict__ T,
                                              unsigned short* __restrict__ xb,
                                              unsigned short* __restrict__ tt) {
    __shared__ unsigned short sm[64][TPAD];
    const int blk = blockIdx.x, tid = threadIdx.x;
    if (blk < 512) {
        const int k0 = (blk & 15) * 64, n0 = (blk >> 4) * 64;
        {   // coalesced read: 64 k-rows x 64 n-cols
            const int r = tid >> 2, cg = (tid & 3) * 16;
            const float* src = &T[(k0 + r) * TCOLS + n0 + cg];
            #pragma unroll
            for (int u = 0; u < 4; ++u) {
                float4 v = *reinterpret_cast<const float4*>(src + u * 4);
                sm[r][cg + u*4 + 0] = bf_trunc(v.x);
                sm[r][cg + u*4 + 1] = bf_trunc(v.y);
                sm[r][cg + u*4 + 2] = bf_trunc(v.z);
                sm[r][cg + u*4 + 3] = bf_trunc(v.w);
            }
        }
        __syncthreads();
        {   // coalesced write: 64 n-rows x 64 k-cols
            const int n = tid >> 2, kg = (tid & 3) * 16;
            unsigned int pk[8];
            #pragma unroll
            for (int j = 0; j < 8; ++j)
                pk[j] = (unsigned int)sm[kg + 2*j][n] |
                        ((unsigned int)sm[kg + 2*j + 1][n] << 16);
            uint4* dst = reinterpret_cast<uint4*>(&tt[(n0 + n) * INF + k0 + kg]);
            dst[0] = make_uint4(pk[0], pk[1], pk[2], pk[3]);
            dst[1] = make_uint4(pk[4], pk[5], pk[6], pk[7]);
        }
    } else {
        const int base = (blk - 512) * 4096 + tid * 16;
        unsigned int pk[8];
        #pragma unroll
        for (int u = 0; u < 4; ++u) {
            float4 v = *reinterpret_cast<const float4*>(&x[base + u * 4]);
            pk[u*2]   = pack_bf2(v.x, v.y);
            pk[u*2+1] = pack_bf2(v.z, v.w);
        }
        uint4* dst = reinterpret_cast<uint4*>(&xb[base]);
        dst[0] = make_uint4(pk[0], pk[1], pk[2], pk[3]);
        dst[1] = make_uint4(pk[4], pk[5], pk[6], pk[7]);
    }
}

// ---------------------------------------------------------------- k_gemm
// Block = (o, mq), 256 thr = 4 waves; wave w -> 16x16 m-tile mq*4+w.
// All-bf16 operands, NO LDS staging, NO barrier pre-epilogue: per k-step
// 1 xb load + 1 tt load + 1 MFMA. All 4 waves read identical tt addresses
// (same o) -> L1 broadcast. 512 blocks = 2 blk/CU = 8 waves/CU.
// A[m=l15][k=q*8+j]; B[n=l15][k=q*8+j]; D col=l15, row=q*4+r (m89/m91).
__global__ __launch_bounds__(256) void k_gemm(const unsigned short* __restrict__ xb,
                                              const unsigned short* __restrict__ tt,
                                              __half* __restrict__ mh) {
    const int blk = blockIdx.x;
    const int o   = blk & 127;
    const int mq  = blk >> 7;
    const int tid = threadIdx.x;
    const int wave = tid >> 6, lane = tid & 63;
    const int l15 = lane & 15, q = lane >> 4;

    __shared__ __half pmout[64][16];     // 2 KB repack buffer

    const int mt = mq * 4 + wave;
    const short8* ap = reinterpret_cast<const short8*>(&xb[(mt * 16 + l15) * INF + q * 8]);
    const short8* bp = reinterpret_cast<const short8*>(&tt[(o * 16 + l15) * INF + q * 8]);

    f32x4 acc = {0.f, 0.f, 0.f, 0.f};
    #pragma unroll 8
    for (int ks = 0; ks < 32; ++ks) {
        short8 a = ap[ks * 4];           // advance 32 k = 4 short8
        short8 b = bp[ks * 4];
        acc = __builtin_amdgcn_mfma_f32_16x16x32_bf16(a, b, acc, 0, 0, 0);
    }

    #pragma unroll
    for (int r = 0; r < 4; ++r)
        pmout[wave * 16 + q * 4 + r][l15] = __float2half(acc[r]);
    __syncthreads();

    // coalesced copy-out -> mh[o][mq*64 + row][*]  (pairwise-native layout)
    if (tid < 128) {
        const int row = tid >> 1, hh = tid & 1;
        uint4 v = *reinterpret_cast<const uint4*>(&pmout[row][hh * 8]);
        *reinterpret_cast<uint4*>(&mh[o * (BATCH * KDIM) + (mq * 64 + row) * KDIM + hh * 8]) = v;
    }
}

// ---------------------------------------------------------------- k_pair
// Block = (o, h), 1024 thr. Thread: i1 = tid&31, bsel = tid>>5 (0..31);
// owns 4 b1-rows {h*128 + r*32 + i1} vs b2 in [bsel*8, bsel*8+8).
// Min-trick: norm = S1+S2-2*sum_k min; arg folded to exp2 form.
#define L2E  1.4426950408889634f
#define TL2E 2.8853900817779268f

// shared chain: sum over 16 halfs of min(A,B), fixed op order (also used
// with A==B for the S precompute -> self-pair cancels to ~1e-5).
__device__ inline float ms_chain(const __half2* A, const __half2* B) {
    __half2 m0 = hmin2(A[0], B[0]);
    __half2 m1 = hmin2(A[1], B[1]);
    __half2 m2 = hmin2(A[2], B[2]);
    __half2 m3 = hmin2(A[3], B[3]);
    m0 = __hadd2(m0, hmin2(A[4], B[4]));
    m1 = __hadd2(m1, hmin2(A[5], B[5]));
    m2 = __hadd2(m2, hmin2(A[6], B[6]));
    m3 = __hadd2(m3, hmin2(A[7], B[7]));
    __half2 es = __hadd2(__hadd2(m0, m1), __hadd2(m2, m3));
    return __low2float(es) + __high2float(es);
}

__global__ __launch_bounds__(1024) void k_pair(const float* __restrict__ x,
                                               const __half* __restrict__ mh,
                                               float* __restrict__ out) {
    const int blk = blockIdx.x;
    const int o   = blk & 127;
    const int h   = blk >> 7;
    const int tid = threadIdx.x;

    __shared__ __half2 pm[BATCH][8];      //  8 KB
    __shared__ float Sl2[BATCH];          //  1 KB: log2e * sum_k m[b][k]
    __shared__ float part[32][128];       // 16 KB  [bsel][b1-local]

    // prologue: copy x row blk into out (cols 0..1023)
    if (tid < 256)
        reinterpret_cast<float4*>(out)[blk * 288 + tid] =
            reinterpret_cast<const float4*>(x)[blk * 256 + tid];

    // load m-slice: contiguous 8 KB, 512 x uint4
    if (tid < 512) {
        uint4 v = *reinterpret_cast<const uint4*>(
            &mh[o * (BATCH * KDIM) + (tid >> 1) * KDIM + (tid & 1) * 8]);
        *reinterpret_cast<uint4*>(&pm[tid >> 1][(tid & 1) * 4]) = v;
    }
    __syncthreads();

    // S precompute: Sl2[b] = log2e * ms_chain(row, row)  (min(a,a)=a exact)
    if (tid < 256) {
        union { uint4 u[2]; __half2 hh[8]; } c;
        c.u[0] = *reinterpret_cast<const uint4*>(&pm[tid][0]);
        c.u[1] = *reinterpret_cast<const uint4*>(&pm[tid][4]);
        Sl2[tid] = L2E * ms_chain(c.hh, c.hh);
    }

    const int i1 = tid & 31;
    const int bsel = tid >> 5;            // 0..31
    __half2 my[4][8];
    #pragma unroll
    for (int r = 0; r < 4; ++r) {
        union { uint4 u[2]; __half2 hh[8]; } c;
        c.u[0] = *reinterpret_cast<const uint4*>(&pm[h * 128 + r * 32 + i1][0]);
        c.u[1] = *reinterpret_cast<const uint4*>(&pm[h * 128 + r * 32 + i1][4]);
        #pragma unroll
        for (int j = 0; j < 8; ++j) my[r][j] = c.hh[j];
    }
    __syncthreads();                      // Sl2 ready

    float nsl1[4];
    #pragma unroll
    for (int r = 0; r < 4; ++r) nsl1[r] = -Sl2[h * 128 + r * 32 + i1];

    float tot[4] = {0.f, 0.f, 0.f, 0.f};
    const int b2_lo = bsel * 8;
    #pragma unroll
    for (int b2 = b2_lo; b2 < b2_lo + 8; ++b2) {
        union { uint4 u[2]; __half2 hh[8]; } co;      // wave-uniform -> broadcast
        co.u[0] = *reinterpret_cast<const uint4*>(&pm[b2][0]);
        co.u[1] = *reinterpret_cast<const uint4*>(&pm[b2][4]);
        const float sb2 = Sl2[b2];                    // wave-uniform
        #pragma unroll
        for (int r = 0; r < 4; ++r) {
            float msf = ms_chain(my[r], co.hh);
            // exp(-(S1+S2-2ms)) = exp2(2*L2E*ms - L2E*S1 - L2E*S2)
            float arg = fmaf(TL2E, msf, nsl1[r] - sb2);
            tot[r] += __builtin_amdgcn_exp2f(arg);  // b2==b1: arg ~ +-1e-5 -> ~1
        }
    }
    #pragma unroll
    for (int r = 0; r < 4; ++r)
        part[bsel][r * 32 + i1] = tot[r];
    __syncthreads();

    // epilogue: sum 32 bsel partials; -1 removes self-pair. One writer per (b,o).
    if (tid < 128) {
        float s = -1.0f;
        #pragma unroll
        for (int j = 0; j < 32; ++j) s += part[j][tid];
        out[(h * 128 + tid) * OCOLS + INF + o] = s;
    }
}

// ---------------------------------------------------------------- launch
extern "C" void kernel_launch(void* const* d_in, const int* in_sizes, int n_in,
                              void* d_out, int out_size, void* d_ws, size_t ws_size,
                              hipStream_t stream) {
    const float* x = (const float*)d_in[0];   // [256][1024]
    const float* T = (const float*)d_in[1];   // [1024][2048]
    float* out = (float*)d_out;               // [256][1152]

    unsigned short* xb = (unsigned short*)d_ws;                              // 512 KB
    unsigned short* tt = (unsigned short*)((char*)d_ws + (512u << 10));      // 4 MB
    __half*         mh = (__half*)((char*)d_ws + (512u << 10) + (4u << 20)); // 1 MB

    k_prep<<<576, 256, 0, stream>>>(x, T, xb, tt);
    k_gemm<<<512, 256, 0, stream>>>(xb, tt, mh);
    k_pair<<<256, 1024, 0, stream>>>(x, mh, out);
}